// Round 5
// baseline (31.363 us; speedup 1.0000x reference)
//
#include <hip/hip_runtime.h>
#include <hip/hip_bf16.h>
#include <cstdint>

#define WAVES 4

typedef float fx4 __attribute__((ext_vector_type(4)));

// Lattice VQ. Per 64-row group (one wave):
//   pass A1 (lane=row): triangular reduction -> r, C=||r||^2/8, bnw[n]=basis[n].(-r/4);
//                       publish {C,bnw} per row to LDS.
//   pass B  (lane=j/4): for each row r (ascending), broadcast-read {C,bnw}, compute
//                       dists for j=4*lane..4*lane+3, store ONE contiguous 1KB row per
//                       global_store_dwordx4 -> wave's 64KB dist block is a pure
//                       sequential write stream (DRAM-friendly, like fillBuffer).
//   pass A2 (lane=row): Gray-code walk over 256 offsets, registers only, arithmetic
//                       bit-identical to the validated kernel -> jmin stable (absmax 8).
//   epilogue: x_hat = (x - r) + g[jmin] to both outputs.
__global__ __launch_bounds__(256) void lvq_main(
    const float* __restrict__ x,
    const float* __restrict__ bp,
    float* __restrict__ oxh0,
    float* __restrict__ oxh1,
    float* __restrict__ odist,
    int B)
{
    __shared__ __align__(16) float sbasis[8][8];     // tril(bp)/|det|
    __shared__ __align__(16) float sgrid[256][8];    // g_j = grid[j] @ basis
    __shared__ __align__(16) float scg2[256];        // |g|^2/8, Gray-permuted (pass A2)
    __shared__ __align__(16) float scg2lin[256];     // |g|^2/8, linear j (pass B)
    __shared__ __align__(16) float sprow[WAVES][64][12]; // {C, bnw[0..7]} per row

    const int tid  = threadIdx.x;
    const int lane = tid & 63;
    const int wid  = tid >> 6;

    // ---- setup: normalized basis ----
    if (tid < 64) {
        const int i = tid >> 3, k = tid & 7;
        float det = 1.f;
        #pragma unroll
        for (int d = 0; d < 8; ++d) det *= bp[d * 8 + d];
        const float ad = fabsf(det);
        sbasis[i][k] = (k <= i) ? (bp[i * 8 + k] / ad) : 0.f;
    }
    __syncthreads();

    // ---- setup: codebook offsets and |g|^2/8 tables ----
    {
        const int j = tid;  // 256 threads
        float g[8];
        #pragma unroll
        for (int k = 0; k < 8; ++k) {
            float s = 0.f;
            #pragma unroll
            for (int n = 0; n < 8; ++n)
                if ((j >> (7 - n)) & 1) s += sbasis[n][k];
            g[k] = s;
            sgrid[j][k] = s;
        }
        float g2 = 0.f;
        #pragma unroll
        for (int k = 0; k < 8; ++k) g2 += g[k] * g[k];
        int t = j; t ^= t >> 1; t ^= t >> 2; t ^= t >> 4; // inverse Gray
        scg2[t] = g2 * 0.125f;
        scg2lin[j] = g2 * 0.125f;
    }
    __syncthreads();

    const int group = blockIdx.x * WAVES + wid;
    const int b0 = group * 64;
    if (b0 >= B) return;
    const int b = b0 + lane;

    // ---- load x row (32 B per lane, coalesced) ----
    const float4* xp = reinterpret_cast<const float4*>(x + (size_t)b * 8);
    const float4 xa = xp[0], xb_ = xp[1];
    float xv[8] = {xa.x, xa.y, xa.z, xa.w, xb_.x, xb_.y, xb_.z, xb_.w};

    // ---- pass A1: triangular basis reduction ----
    float xt[8];
    #pragma unroll
    for (int k = 0; k < 8; ++k) xt[k] = xv[k];
    float r[8];
    #pragma unroll
    for (int i = 7; i >= 0; --i) {
        const float bii = sbasis[i][i];
        const float ui = floorf(xt[i] / bii);
        r[i] = xt[i] - ui * bii;      // residual coord (x - dot@basis)
        #pragma unroll
        for (int k = 0; k < i; ++k) xt[k] -= ui * sbasis[i][k];
    }
    float C = 0.f;
    #pragma unroll
    for (int k = 0; k < 8; ++k) C += r[k] * r[k];
    C *= 0.125f;                       // ||r||^2 / 8
    float w[8];
    #pragma unroll
    for (int k = 0; k < 8; ++k) w[k] = -0.25f * r[k];
    float bnw[8];                      // basis[n,:] . w
    #pragma unroll
    for (int n = 0; n < 8; ++n) {
        float s = 0.f;
        #pragma unroll
        for (int k = 0; k <= n; ++k) s += sbasis[n][k] * w[k];
        bnw[n] = s;
    }

    // publish {C, bnw} for this row (48B per lane, 16B-aligned)
    {
        fx4 q0; q0.x = C;      q0.y = bnw[0]; q0.z = bnw[1]; q0.w = bnw[2];
        fx4 q1; q1.x = bnw[3]; q1.y = bnw[4]; q1.z = bnw[5]; q1.w = bnw[6];
        *reinterpret_cast<fx4*>(&sprow[wid][lane][0]) = q0;
        *reinterpret_cast<fx4*>(&sprow[wid][lane][4]) = q1;
        sprow[wid][lane][8] = bnw[7];
    }
    __syncthreads();

    // ---- pass B: sequential dist stream, lane owns j = 4*lane .. 4*lane+3 ----
    {
        // lane-constant bit selectors for dims 0..5 (j bits 7..2 == lane bits 5..0)
        float fb[6];
        #pragma unroll
        for (int n = 0; n < 6; ++n) fb[n] = (float)((lane >> (5 - n)) & 1);
        const fx4 cgv = *reinterpret_cast<const fx4*>(&scg2lin[4 * lane]);

        float* orow = odist + (size_t)b0 * 256;
        #pragma unroll 8
        for (int rr = 0; rr < 64; ++rr) {
            const fx4 a  = *reinterpret_cast<const fx4*>(&sprow[wid][rr][0]); // C,b0,b1,b2
            const fx4 bq = *reinterpret_cast<const fx4*>(&sprow[wid][rr][4]); // b3,b4,b5,b6
            const float b7 = sprow[wid][rr][8];
            float base = a.x;
            base = fmaf(fb[0], a.y, base);
            base = fmaf(fb[1], a.z, base);
            base = fmaf(fb[2], a.w, base);
            base = fmaf(fb[3], bq.x, base);
            base = fmaf(fb[4], bq.y, base);
            base = fmaf(fb[5], bq.z, base);
            const float t7  = base + b7;
            const float t6  = base + bq.w;
            const float t67 = t6 + b7;
            fx4 v;
            v.x = base + cgv.x;
            v.y = t7  + cgv.y;
            v.z = t6  + cgv.z;
            v.w = t67 + cgv.w;
            fx4* gdst = reinterpret_cast<fx4*>(orow + (size_t)rr * 256);
            gdst[lane] = v;
        }
    }

    // ---- pass A2: Gray-walk argmin (registers only, bit-identical arithmetic) ----
    float acc = 0.f;                   // g_j . w, updated incrementally
    float md = 3.4e38f;
    int jmin = 0;

    for (int c = 0; c < 8; ++c) {
        // chunk-boundary Gray step: flips j-bit p = 5 + ctz(c) -> dim 2-ctz(c)
        if (c) {
            const int p2 = __builtin_ctz(c);
            const float delta = (p2 == 0) ? bnw[2] : ((p2 == 1) ? bnw[1] : bnw[0]);
            const int gb = ((c ^ (c >> 1)) >> p2) & 1;
            acc = gb ? (acc + delta) : (acc - delta);
        }
        const int jb   = (c ^ (c >> 1)) << 5;        // j-block of this chunk
        const int fix4 = (c & 1) << 4;               // bit-4 parity fixup (column)
        const float bn3s = (c & 1) ? -bnw[3] : bnw[3];

        #pragma unroll
        for (int m = 0; m < 8; ++m) {
            const float4 c4 = *reinterpret_cast<const float4*>(&scg2[c * 32 + m * 4]);
            const float cg[4] = {c4.x, c4.y, c4.z, c4.w};
            #pragma unroll
            for (int s = 0; s < 4; ++s) {
                const int tp = 4 * m + s;
                if (tp == 16) {
                    acc += bn3s;
                } else if (tp > 0) {
                    const int p = __builtin_ctz(tp);     // compile-time
                    const int sgn = ((tp ^ (tp >> 1)) >> p) & 1;
                    const int n = 7 - p;
                    acc = sgn ? (acc + bnw[n]) : (acc - bnw[n]);
                }
                const float d = (C + cg[tp & 3]) + acc;
                const int jlow = ((tp ^ (tp >> 1)) & 15) | (tp & 16);
                const int j = jb ^ fix4 ^ jlow;
                if (d < md) { md = d; jmin = j; }
            }
        }
    }

    // ---- x_hat = (x - r) + g[jmin], written to both outputs ----
    const float4 ga = *reinterpret_cast<const float4*>(&sgrid[jmin][0]);
    const float4 gb2 = *reinterpret_cast<const float4*>(&sgrid[jmin][4]);
    const float gm[8] = {ga.x, ga.y, ga.z, ga.w, gb2.x, gb2.y, gb2.z, gb2.w};
    float xh[8];
    #pragma unroll
    for (int k = 0; k < 8; ++k) xh[k] = (xv[k] - r[k]) + gm[k];
    const float4 h0 = make_float4(xh[0], xh[1], xh[2], xh[3]);
    const float4 h1 = make_float4(xh[4], xh[5], xh[6], xh[7]);
    reinterpret_cast<float4*>(oxh0 + (size_t)b * 8)[0] = h0;
    reinterpret_cast<float4*>(oxh0 + (size_t)b * 8)[1] = h1;
    reinterpret_cast<float4*>(oxh1 + (size_t)b * 8)[0] = h0;
    reinterpret_cast<float4*>(oxh1 + (size_t)b * 8)[1] = h1;
}

extern "C" void kernel_launch(void* const* d_in, const int* in_sizes, int n_in,
                              void* d_out, int out_size, void* d_ws, size_t ws_size,
                              hipStream_t stream) {
    const float* x  = (const float*)d_in[0];
    const float* bp = (const float*)d_in[1];
    const int B = in_sizes[0] / 8;                 // 131072
    float* out   = (float*)d_out;
    float* oxh0  = out;
    float* oxh1  = out + (size_t)B * 8;
    float* odist = out + (size_t)2 * B * 8;
    const int groups = (B + 63) / 64;
    const int blocks = (groups + WAVES - 1) / WAVES;
    lvq_main<<<blocks, 256, 0, stream>>>(x, bp, oxh0, oxh1, odist, B);
}

// Round 6
// 29.196 us; speedup vs baseline: 1.0742x; 1.0742x over previous
//
#include <hip/hip_runtime.h>
#include <hip/hip_bf16.h>
#include <cstdint>

#define WAVES 4

typedef float fx4 __attribute__((ext_vector_type(4)));

// Lattice VQ: per row, triangular-reduce x, then scan 256 codebook offsets in
// Gray-code order with incremental dot-product updates (arithmetic frozen since
// round 1 -> stable argmin, absmax 8.0). Lane = row; dists staged in a SINGLE
// per-wave LDS buffer; at each chunk start the previous chunk is bulk-read into
// registers (one amortized lgkm wait), and stores issue evenly from VGPRs.
__global__ __launch_bounds__(256) void lvq_main(
    const float* __restrict__ x,
    const float* __restrict__ bp,
    float* __restrict__ oxh0,
    float* __restrict__ oxh1,
    float* __restrict__ odist,
    int B)
{
    __shared__ __align__(16) float sbasis[8][8];     // tril(bp)/|det|
    __shared__ __align__(16) float sgrid[256][8];    // g_j = grid[j] @ basis
    __shared__ __align__(16) float scg2[256];        // |g|^2/8, Gray-permuted
    __shared__ __align__(16) fx4 sbufv[WAVES][64][8]; // dist staging (single buf)

    const int tid  = threadIdx.x;
    const int lane = tid & 63;
    const int wid  = tid >> 6;

    // ---- setup: normalized basis ----
    if (tid < 64) {
        const int i = tid >> 3, k = tid & 7;
        float det = 1.f;
        #pragma unroll
        for (int d = 0; d < 8; ++d) det *= bp[d * 8 + d];
        const float ad = fabsf(det);
        sbasis[i][k] = (k <= i) ? (bp[i * 8 + k] / ad) : 0.f;
    }
    __syncthreads();

    // ---- setup: codebook offsets and Gray-ordered |g|^2/8 table ----
    {
        const int j = tid;  // 256 threads
        float g[8];
        #pragma unroll
        for (int k = 0; k < 8; ++k) {
            float s = 0.f;
            #pragma unroll
            for (int n = 0; n < 8; ++n)
                if ((j >> (7 - n)) & 1) s += sbasis[n][k];
            g[k] = s;
            sgrid[j][k] = s;
        }
        float g2 = 0.f;
        #pragma unroll
        for (int k = 0; k < 8; ++k) g2 += g[k] * g[k];
        int t = j; t ^= t >> 1; t ^= t >> 2; t ^= t >> 4; // inverse Gray
        scg2[t] = g2 * 0.125f;
    }
    __syncthreads();

    const int group = blockIdx.x * WAVES + wid;
    const int b0 = group * 64;
    if (b0 >= B) return;
    const int b = b0 + lane;

    // ---- load x row (32 B per lane, coalesced) ----
    const float4* xp = reinterpret_cast<const float4*>(x + (size_t)b * 8);
    const float4 xa = xp[0], xb_ = xp[1];
    float xv[8] = {xa.x, xa.y, xa.z, xa.w, xb_.x, xb_.y, xb_.z, xb_.w};

    // ---- triangular basis reduction (exact for this data) ----
    float xt[8];
    #pragma unroll
    for (int k = 0; k < 8; ++k) xt[k] = xv[k];
    float r[8];
    #pragma unroll
    for (int i = 7; i >= 0; --i) {
        const float bii = sbasis[i][i];
        const float ui = floorf(xt[i] / bii);
        r[i] = xt[i] - ui * bii;      // residual coord (x - dot@basis)
        #pragma unroll
        for (int k = 0; k < i; ++k) xt[k] -= ui * sbasis[i][k];
    }
    float C = 0.f;
    #pragma unroll
    for (int k = 0; k < 8; ++k) C += r[k] * r[k];
    C *= 0.125f;                       // ||r||^2 / 8
    float w[8];
    #pragma unroll
    for (int k = 0; k < 8; ++k) w[k] = -0.25f * r[k];
    float bnw[8];                      // basis[n,:] . w
    #pragma unroll
    for (int n = 0; n < 8; ++n) {
        float s = 0.f;
        #pragma unroll
        for (int k = 0; k <= n; ++k) s += sbasis[n][k] * w[k];
        bnw[n] = s;
    }

    float acc = 0.f;                   // g_j . w, updated incrementally
    float md = 3.4e38f;
    int jmin = 0;
    const int g = lane & 7, K = lane >> 3;   // flush roles
    int jb_prev = 0, fix2_prev = 0;

    for (int c = 0; c < 8; ++c) {
        // chunk-boundary Gray step: flips j-bit p = 5 + ctz(c) -> dim 2-ctz(c)
        if (c) {
            const int p2 = __builtin_ctz(c);
            const float delta = (p2 == 0) ? bnw[2] : ((p2 == 1) ? bnw[1] : bnw[0]);
            const int gb = ((c ^ (c >> 1)) >> p2) & 1;
            acc = gb ? (acc + delta) : (acc - delta);
        }
        const int jb   = (c ^ (c >> 1)) << 5;        // j-block of this chunk
        const int fix4 = (c & 1) << 4;               // bit-4 parity fixup (column)
        const int fix2 = (c & 1) << 2;               // same fixup as group index
        const float bn3s = (c & 1) ? -bnw[3] : bnw[3];

        // bulk-read previous chunk into registers BEFORE any writes of this
        // chunk (per-wave in-order LDS => single buffer is race-free).
        fx4 fr[8];
        if (c > 0) {
            #pragma unroll
            for (int m = 0; m < 8; ++m)
                fr[m] = sbufv[wid][K + 8 * m][(g ^ fix2_prev) ^ K];
        }
        fx4* gdst_prev = reinterpret_cast<fx4*>(odist + (size_t)(b0 + K) * 256 + jb_prev) + g;

        #pragma unroll
        for (int m = 0; m < 8; ++m) {
            const float4 c4 = *reinterpret_cast<const float4*>(&scg2[c * 32 + m * 4]);
            const float cg[4] = {c4.x, c4.y, c4.z, c4.w};
            float va[4];
            #pragma unroll
            for (int s = 0; s < 4; ++s) {
                const int tp = 4 * m + s;
                // acc update: arithmetic order identical to validated version
                if (tp == 16) {
                    acc += bn3s;
                } else if (tp > 0) {
                    const int p = __builtin_ctz(tp);     // compile-time
                    const int sgn = ((tp ^ (tp >> 1)) >> p) & 1;
                    const int n = 7 - p;
                    acc = sgn ? (acc + bnw[n]) : (acc - bnw[n]);
                }
                const float d = (C + cg[tp & 3]) + acc;
                const int slot2 = (s ^ (s >> 1)) ^ ((m & 1) << 1); // compile-time
                va[slot2] = d;
                const int jlow = ((tp ^ (tp >> 1)) & 15) | (tp & 16);
                const int j = jb ^ fix4 ^ jlow;
                if (d < md) { md = d; jmin = j; }
            }
            // slot group for this m (jlow>>2), XOR-swizzled by row for banks
            const int Q = (m & 4) | ((m ^ (m >> 1)) & 3);
            fx4 v4;
            v4.x = va[0]; v4.y = va[1]; v4.z = va[2]; v4.w = va[3];
            sbufv[wid][lane][Q ^ (lane & 7)] = v4;

            // pipelined flush from registers: one coalesced store per m-step
            if (c > 0) gdst_prev[m * 512] = fr[m];
        }
        jb_prev = jb; fix2_prev = fix2;
    }
    // ---- tail flush of chunk 7 ----
    {
        fx4* gdst = reinterpret_cast<fx4*>(odist + (size_t)(b0 + K) * 256 + jb_prev) + g;
        #pragma unroll
        for (int m = 0; m < 8; ++m) {
            const fx4 vf = sbufv[wid][K + 8 * m][(g ^ fix2_prev) ^ K];
            gdst[m * 512] = vf;
        }
    }

    // ---- x_hat = (x - r) + g[jmin], written to both outputs ----
    const float4 ga = *reinterpret_cast<const float4*>(&sgrid[jmin][0]);
    const float4 gb2 = *reinterpret_cast<const float4*>(&sgrid[jmin][4]);
    const float gm[8] = {ga.x, ga.y, ga.z, ga.w, gb2.x, gb2.y, gb2.z, gb2.w};
    float xh[8];
    #pragma unroll
    for (int k = 0; k < 8; ++k) xh[k] = (xv[k] - r[k]) + gm[k];
    const float4 h0 = make_float4(xh[0], xh[1], xh[2], xh[3]);
    const float4 h1 = make_float4(xh[4], xh[5], xh[6], xh[7]);
    reinterpret_cast<float4*>(oxh0 + (size_t)b * 8)[0] = h0;
    reinterpret_cast<float4*>(oxh0 + (size_t)b * 8)[1] = h1;
    reinterpret_cast<float4*>(oxh1 + (size_t)b * 8)[0] = h0;
    reinterpret_cast<float4*>(oxh1 + (size_t)b * 8)[1] = h1;
}

extern "C" void kernel_launch(void* const* d_in, const int* in_sizes, int n_in,
                              void* d_out, int out_size, void* d_ws, size_t ws_size,
                              hipStream_t stream) {
    const float* x  = (const float*)d_in[0];
    const float* bp = (const float*)d_in[1];
    const int B = in_sizes[0] / 8;                 // 131072
    float* out   = (float*)d_out;
    float* oxh0  = out;
    float* oxh1  = out + (size_t)B * 8;
    float* odist = out + (size_t)2 * B * 8;
    const int groups = (B + 63) / 64;
    const int blocks = (groups + WAVES - 1) / WAVES;
    lvq_main<<<blocks, 256, 0, stream>>>(x, bp, oxh0, oxh1, odist, B);
}